// Round 4
// baseline (285.455 us; speedup 1.0000x reference)
//
#include <hip/hip_runtime.h>
#include <stdint.h>

typedef __attribute__((ext_vector_type(8))) short short8;
typedef __attribute__((ext_vector_type(4))) float float4v;

#define HW   4096
#define CC   256
#define SEQQ 32
#define BSZ  32
#define ROWS 64
#define PSTR 48   // padded row stride (shorts) for pL: 96 B, 16B-aligned

// bf16 helpers (round-to-nearest-even)
static __device__ __forceinline__ uint16_t f2bf(float f) {
  union { float f; uint32_t u; } v; v.f = f;
  uint32_t r = v.u + 0x7FFFu + ((v.u >> 16) & 1u);
  return (uint16_t)(r >> 16);
}
static __device__ __forceinline__ float bf2f(uint16_t h) {
  union { uint32_t u; float f; } v; v.u = ((uint32_t)h) << 16;
  return v.f;
}

// ---------------------------------------------------------------------------
// Prep: ctx = context @ W (fp32 accum), emitted as MFMA *fragment-ordered*
// bf16 arrays so attn_main can load B-fragments straight from global:
//   hiF/loF[b][k0][t][lane] : phase-1 B-frags (hi/lo split), short8 per lane
//   tF  [b][ct][lane]       : phase-2 B-frags, short8 per lane
// plus mask -> additive f32 bias. grid: 257 x 256.
// ---------------------------------------------------------------------------
extern "C" __global__ __launch_bounds__(256) void prep_kernel(
    const float* __restrict__ ctx_in,   // [32][32][256]
    const float* __restrict__ Wp,       // [256][256]
    const void*  __restrict__ mask,     // [32][32] unknown storage
    float* __restrict__ bias_ws,        // [32][32] f32
    uint16_t* __restrict__ hiF_ws,      // [32][8][2][64][8] bf16
    uint16_t* __restrict__ loF_ws,      // [32][8][2][64][8] bf16
    uint16_t* __restrict__ tF_ws)       // [32][16][64][8] bf16
{
  const int t = threadIdx.x;
  if (blockIdx.x == 256) {
    // --- mask storage detection + bias ---
    __shared__ int byteFlag;
    if (t == 0) byteFlag = 0;
    __syncthreads();
    const uint8_t* mb = (const uint8_t*)mask;
    int nz = 0;
    for (int i = t; i < 1024; i += 256)
      if ((i & 3) == 1 && mb[i] != 0) nz = 1;
    if (nz) atomicOr(&byteFlag, 1);
    __syncthreads();
    const bool byteMode = (byteFlag != 0);
    const uint32_t* mw = (const uint32_t*)mask;
    for (int i = t; i < 1024; i += 256) {
      bool m = byteMode ? (mb[i] != 0) : (mw[i] != 0);
      bias_ws[i] = m ? -1e30f : 0.0f;
    }
    return;
  }

  // --- projection: 4 rows of [1024][256] output; thread t owns channel c=t ---
  const int r0 = blockIdx.x * 4;
  __shared__ float crow[4][CC];
  #pragma unroll
  for (int j = 0; j < 4; ++j)
    crow[j][t] = ctx_in[(size_t)(r0 + j) * CC + t];
  __syncthreads();

  float acc[4] = {0.f, 0.f, 0.f, 0.f};
  for (int d = 0; d < CC; ++d) {
    float wv = Wp[(size_t)d * CC + t];
    #pragma unroll
    for (int j = 0; j < 4; ++j) acc[j] += crow[j][d] * wv;
  }

  const int c  = t;
  const int k0 = c >> 5, qd = (c >> 3) & 3, jj = c & 7;   // phase-1 coords
  const int ct = c >> 4, l15c = c & 15;                    // phase-2 coords
  #pragma unroll
  for (int j = 0; j < 4; ++j) {
    int row = r0 + j;              // row = b*32 + s
    int b = row >> 5, s = row & 31;
    float v = acc[j];
    uint16_t h  = f2bf(v);
    uint16_t lo = f2bf(v - bf2f(h));
    // phase-1 frag: lane = qd*16 + (s&15), tile t = s>>4, element jj
    size_t i1 = ((((size_t)b * 8 + k0) * 2 + (s >> 4)) * 64 + qd * 16 + (s & 15)) * 8 + jj;
    hiF_ws[i1] = h;
    loF_ws[i1] = lo;
    // phase-2 frag: lane = (s>>3)*16 + (c&15), element s&7
    size_t i2 = (((size_t)b * 16 + ct) * 64 + (s >> 3) * 16 + l15c) * 8 + (s & 7);
    tF_ws[i2] = h;
  }
}

// ---------------------------------------------------------------------------
// Main fused kernel: block = (64 spatial rows, batch b); 4 waves x 16 rows.
// Phase1: S = X*ctx^T via split-bf16 MFMA, B-frags loaded direct from global
// (L2/L3-hot). Softmax (mask row = n & 31). Phase2: O = P*ctx.
// Only pL lives in LDS -> 6 KB/block, occupancy VGPR-bound.
// ---------------------------------------------------------------------------
extern "C" __global__ __launch_bounds__(256, 5) void attn_main(
    const float* __restrict__ x,        // [32][4096][256]
    const uint8_t* __restrict__ ws,
    float* __restrict__ out0,           // weighted_context [32][4096][256]
    float* __restrict__ out1)           // word_attn        [32][4096][32]
{
  const float*  bias_ws = (const float*)ws;
  const short8* hiF = (const short8*)(ws + 4096);
  const short8* loF = hiF + BSZ * 8 * 2 * 64;
  const short8* tF  = loF + BSZ * 8 * 2 * 64;

  __shared__ __align__(16) uint16_t pL[ROWS * PSTR];

  const int tid = threadIdx.x;
  const int b   = blockIdx.y;
  const int n0  = blockIdx.x * ROWS;

  const int w    = tid >> 6;       // wave id 0..3
  const int lane = tid & 63;
  const int l15  = lane & 15;
  const int quad = lane >> 4;
  const int nbase = n0 + w * 16;

  // ---- phase 1: logits via split-bf16 MFMA ----
  float4v acc0 = {0.f, 0.f, 0.f, 0.f};
  float4v acc1 = {0.f, 0.f, 0.f, 0.f};
  const float*  xrow  = x + ((size_t)b * HW + nbase + l15) * CC + quad * 8;
  const short8* hiF_b = hiF + (size_t)b * 16 * 64 + lane;
  const short8* loF_b = loF + (size_t)b * 16 * 64 + lane;

  for (int k0 = 0; k0 < 8; ++k0) {
    float4 xa = *(const float4*)(xrow + k0 * 32);
    float4 xb = *(const float4*)(xrow + k0 * 32 + 4);
    short8 bh0 = hiF_b[(k0 * 2 + 0) * 64];
    short8 bl0 = loF_b[(k0 * 2 + 0) * 64];
    short8 bh1 = hiF_b[(k0 * 2 + 1) * 64];
    short8 bl1 = loF_b[(k0 * 2 + 1) * 64];
    float xv[8] = {xa.x, xa.y, xa.z, xa.w, xb.x, xb.y, xb.z, xb.w};
    short8 ah, al;
    #pragma unroll
    for (int j = 0; j < 8; ++j) {
      uint16_t h = f2bf(xv[j]);
      ah[j] = (short)h;
      al[j] = (short)f2bf(xv[j] - bf2f(h));
    }
    acc0 = __builtin_amdgcn_mfma_f32_16x16x32_bf16(ah, bh0, acc0, 0, 0, 0);
    acc0 = __builtin_amdgcn_mfma_f32_16x16x32_bf16(ah, bl0, acc0, 0, 0, 0);
    acc0 = __builtin_amdgcn_mfma_f32_16x16x32_bf16(al, bh0, acc0, 0, 0, 0);
    acc1 = __builtin_amdgcn_mfma_f32_16x16x32_bf16(ah, bh1, acc1, 0, 0, 0);
    acc1 = __builtin_amdgcn_mfma_f32_16x16x32_bf16(ah, bl1, acc1, 0, 0, 0);
    acc1 = __builtin_amdgcn_mfma_f32_16x16x32_bf16(al, bh1, acc1, 0, 0, 0);
  }

  // ---- softmax over 32 logits per row (row m = quad*4+r, col s = l15/+16) ----
  #pragma unroll
  for (int r = 0; r < 4; ++r) {
    const int n  = nbase + quad * 4 + r;
    const int br = n & 31;                     // mask-tile quirk: row = n % 32
    float v0 = acc0[r] + bias_ws[br * 32 + l15];
    float v1 = acc1[r] + bias_ws[br * 32 + 16 + l15];
    float mx = fmaxf(v0, v1);
    #pragma unroll
    for (int off = 1; off < 16; off <<= 1)
      mx = fmaxf(mx, __shfl_xor(mx, off, 64));
    float e0 = __expf(v0 - mx);
    float e1 = __expf(v1 - mx);
    float sm = e0 + e1;
    #pragma unroll
    for (int off = 1; off < 16; off <<= 1)
      sm += __shfl_xor(sm, off, 64);
    float inv = 1.0f / sm;
    float p0 = e0 * inv, p1 = e1 * inv;
    size_t o1 = ((size_t)b * HW + n) * SEQQ;
    out1[o1 + l15]      = p0;
    out1[o1 + 16 + l15] = p1;
    pL[(w * 16 + quad * 4 + r) * PSTR + l15]      = f2bf(p0);
    pL[(w * 16 + quad * 4 + r) * PSTR + 16 + l15] = f2bf(p1);
  }
  __syncthreads();   // make pL writes visible before fragment reads

  // ---- phase 2: O = P * ctx  (K=32 in one MFMA per 16x16 tile) ----
  short8 pa = *(const short8*)&pL[(w * 16 + l15) * PSTR + quad * 8];
  const short8* tF_b = tF + (size_t)b * 16 * 64 + lane;
  #pragma unroll 4
  for (int ct = 0; ct < 16; ++ct) {
    short8 bfr = tF_b[ct * 64];
    float4v z = {0.f, 0.f, 0.f, 0.f};
    float4v d = __builtin_amdgcn_mfma_f32_16x16x32_bf16(pa, bfr, z, 0, 0, 0);
    #pragma unroll
    for (int r = 0; r < 4; ++r) {
      size_t o0 = ((size_t)b * HW + nbase + quad * 4 + r) * CC + ct * 16 + l15;
      out0[o0] = d[r];
    }
  }
}

// ---------------------------------------------------------------------------
extern "C" void kernel_launch(void* const* d_in, const int* in_sizes, int n_in,
                              void* d_out, int out_size, void* d_ws, size_t ws_size,
                              hipStream_t stream) {
  const float* x      = (const float*)d_in[0];
  // d_in[1] = sentence (unused by reference call())
  const float* ctx_in = (const float*)d_in[2];
  const void*  mask   = d_in[3];
  const float* Wp     = (const float*)d_in[4];

  float* out0 = (float*)d_out;                       // [32][4096][256]
  float* out1 = out0 + (size_t)BSZ * HW * CC;        // [32][4096][32]

  uint8_t*  ws     = (uint8_t*)d_ws;
  float*    bias_ws = (float*)ws;                              // 4 KB
  uint16_t* hiF_ws = (uint16_t*)(ws + 4096);                   // 512 KB
  uint16_t* loF_ws = hiF_ws + BSZ * 8 * 2 * 64 * 8;            // 512 KB
  uint16_t* tF_ws  = loF_ws + BSZ * 8 * 2 * 64 * 8;            // 512 KB

  prep_kernel<<<257, 256, 0, stream>>>(ctx_in, Wp, mask, bias_ws,
                                       hiF_ws, loF_ws, tF_ws);
  attn_main<<<dim3(HW / ROWS, BSZ), 256, 0, stream>>>(x, ws, out0, out1);
}